// Round 1
// baseline (887.454 us; speedup 1.0000x reference)
//
#include <hip/hip_runtime.h>
#include <math.h>

#define N_NODES 50000
#define N_EDGES 400000
#define H_HEADS 8
#define D_HEAD 16
#define R_TYPES 6
#define T_TYPES 4
#define DIM 128

// ======================= CSR build (group edges by dst) =======================

__global__ void k_count(const int* __restrict__ dst, int* __restrict__ deg, int n) {
    int e = blockIdx.x * blockDim.x + threadIdx.x;
    if (e < n) atomicAdd(&deg[dst[e]], 1);
}

__global__ void k_scanA(const int* __restrict__ deg, int* __restrict__ offs,
                        int* __restrict__ partial, int n) {
    __shared__ int tmp[256];
    int tid = threadIdx.x;
    int i = blockIdx.x * 256 + tid;
    int v = (i < n) ? deg[i] : 0;
    tmp[tid] = v;
    __syncthreads();
    for (int o = 1; o < 256; o <<= 1) {
        int t = (tid >= o) ? tmp[tid - o] : 0;
        __syncthreads();
        tmp[tid] += t;
        __syncthreads();
    }
    if (i < n) offs[i] = tmp[tid] - v;           // exclusive within block
    if (tid == 255) partial[blockIdx.x] = tmp[255];
}

__global__ void k_scanB(int* __restrict__ partial, int nb) {
    __shared__ int tmp[256];
    int tid = threadIdx.x;
    int v = (tid < nb) ? partial[tid] : 0;
    tmp[tid] = v;
    __syncthreads();
    for (int o = 1; o < 256; o <<= 1) {
        int t = (tid >= o) ? tmp[tid - o] : 0;
        __syncthreads();
        tmp[tid] += t;
        __syncthreads();
    }
    if (tid < nb) partial[tid] = tmp[tid] - v;   // exclusive block offsets
}

__global__ void k_scanC(int* __restrict__ offs, const int* __restrict__ partial, int n) {
    int i = blockIdx.x * 256 + threadIdx.x;
    if (i < n) offs[i] += partial[blockIdx.x];
}

__global__ void k_scatter(const int* __restrict__ dst, int* __restrict__ offs,
                          int* __restrict__ elist, int n) {
    int e = blockIdx.x * blockDim.x + threadIdx.x;
    if (e < n) {
        int pos = atomicAdd(&offs[dst[e]], 1);   // offs becomes END offset after this
        elist[pos] = e;
    }
}

// ======================= K1: typed linear k,q,v =======================
// block = 1 node, 128 threads; x row staged in LDS; each thread computes one
// output column of k,q,v against W[ntype].

__global__ void k_kqv(const float* __restrict__ x, const int* __restrict__ ntype,
                      const float* __restrict__ Wk, const float* __restrict__ Wq,
                      const float* __restrict__ Wv,
                      float* __restrict__ kb, float* __restrict__ qb, float* __restrict__ vb) {
    __shared__ float xs[DIM];
    int i = blockIdx.x;
    int j = threadIdx.x;
    xs[j] = x[i * DIM + j];
    __syncthreads();
    int t = ntype[i];
    const float* wk = Wk + (size_t)t * DIM * DIM;
    const float* wq = Wq + (size_t)t * DIM * DIM;
    const float* wv = Wv + (size_t)t * DIM * DIM;
    float ak = 0.f, aq = 0.f, av = 0.f;
#pragma unroll 4
    for (int d = 0; d < DIM; ++d) {
        float xv = xs[d];
        ak = fmaf(xv, wk[d * DIM + j], ak);
        aq = fmaf(xv, wq[d * DIM + j], aq);
        av = fmaf(xv, wv[d * DIM + j], av);
    }
    kb[i * DIM + j] = ak;
    qb[i * DIM + j] = aq;
    vb[i * DIM + j] = av;
}

// ======================= K2: per-edge attention logits =======================
// thread per (e,h). a[e,h] = (k_src[h] @ rel_att[h,r]) . q_dst[h] * pri[h,r] / 4
// rel_att staged in LDS with layout [d*16+j][h*6+r] to avoid bank conflicts.

__global__ void k_edge_a(const float* __restrict__ kbuf, const float* __restrict__ qbuf,
                         const int* __restrict__ src, const int* __restrict__ dst,
                         const int* __restrict__ etype,
                         const float* __restrict__ rel_att, const float* __restrict__ rel_pri,
                         float* __restrict__ a_ws, int nE) {
    __shared__ float A_l[256 * 48];   // 48 KB
    for (int idx = threadIdx.x; idx < H_HEADS * R_TYPES * 256; idx += 256) {
        int hr = idx >> 8;        // h*6+r
        int dj = idx & 255;       // d*16+j
        A_l[dj * 48 + hr] = rel_att[idx];
    }
    __syncthreads();
    int gid = blockIdx.x * 256 + threadIdx.x;
    int e = gid >> 3;
    int h = gid & 7;
    if (e >= nE) return;
    int s = src[e], dn = dst[e], r = etype[e];
    float kreg[D_HEAD], qreg[D_HEAD];
    const float* kp = kbuf + (size_t)s * DIM + h * D_HEAD;
    const float* qp = qbuf + (size_t)dn * DIM + h * D_HEAD;
#pragma unroll
    for (int d = 0; d < D_HEAD; ++d) { kreg[d] = kp[d]; qreg[d] = qp[d]; }
    int hr = h * R_TYPES + r;
    float acc = 0.f;
#pragma unroll
    for (int j = 0; j < D_HEAD; ++j) {
        float t = 0.f;
#pragma unroll
        for (int d = 0; d < D_HEAD; ++d)
            t = fmaf(kreg[d], A_l[(d * 16 + j) * 48 + hr], t);
        acc = fmaf(t, qreg[j], acc);
    }
    a_ws[(size_t)e * H_HEADS + h] = acc * rel_pri[h * R_TYPES + r] * 0.25f;
}

// ======================= K3: per-node softmax + aggregation =======================
// 1 wave per node; 4 groups of 16 lanes handle 4 heads at a time (2 outer iters).
// exp-weighted v accumulated into per-etype LDS buckets, then R small matmuls
// against rel_msg. Writes h into d_out (scratch).

__global__ void k_aggregate(const float* __restrict__ vbuf, const float* __restrict__ a_ws,
                            const int* __restrict__ offs_end, const int* __restrict__ deg,
                            const int* __restrict__ elist, const int* __restrict__ src,
                            const int* __restrict__ etype,
                            const float* __restrict__ rel_msg,
                            float* __restrict__ hacc, int n) {
    __shared__ float wsum[4][R_TYPES * 4 * 16];   // per wave: [r][group][d]
    int wid = threadIdx.x >> 6;
    int lane = threadIdx.x & 63;
    int node = blockIdx.x * 4 + wid;
    bool valid = node < n;
    int g = lane >> 4;     // head group 0..3
    int d = lane & 15;
    int end = valid ? offs_end[node] : 0;
    int dg  = valid ? deg[node] : 0;
    int start = end - dg;
    float* ws_w = wsum[wid];

    for (int ho = 0; ho < 2; ++ho) {
        int h = ho * 4 + g;
        // zero my bucket slots
        for (int r = 0; r < R_TYPES; ++r) ws_w[r * 64 + g * 16 + d] = 0.f;
        // pass 1: max over incoming edges
        float m = -1e30f;
        for (int p = start; p < end; ++p) {
            int e = elist[p];
            m = fmaxf(m, a_ws[(size_t)e * H_HEADS + h]);
        }
        // pass 2: exp-sum + bucket accumulation
        float den = 0.f;
        for (int p = start; p < end; ++p) {
            int e = elist[p];
            float ex = __expf(a_ws[(size_t)e * H_HEADS + h] - m);
            den += ex;
            int s = src[e], r = etype[e];
            float vv = vbuf[(size_t)s * DIM + h * D_HEAD + d];
            ws_w[r * 64 + g * 16 + d] += ex * vv;
        }
        __syncthreads();
        // final: out[h][d] = (1/den) * sum_r sum_dp wsum[r][g][dp] * M[h][r][dp][d]
        float acc = 0.f;
        for (int r = 0; r < R_TYPES; ++r) {
            const float* M = rel_msg + ((size_t)h * R_TYPES + r) * 256;
#pragma unroll
            for (int dp = 0; dp < 16; ++dp)
                acc = fmaf(ws_w[r * 64 + g * 16 + dp], M[dp * 16 + d], acc);
        }
        if (valid)
            hacc[(size_t)node * DIM + h * D_HEAD + d] = acc / fmaxf(den, 1e-9f);
        __syncthreads();
    }
}

// ======================= K4: output projection + gate + residual + LayerNorm =======================

__global__ void k_final(const float* __restrict__ x, const int* __restrict__ ntype,
                        const float* __restrict__ Wa, const float* __restrict__ skip,
                        const float* __restrict__ gamma, const float* __restrict__ beta,
                        float* __restrict__ out) {
    __shared__ float hs[DIM];
    __shared__ float red[4];
    int i = blockIdx.x;
    int j = threadIdx.x;
    hs[j] = out[(size_t)i * DIM + j];   // h from K3 (d_out used as scratch)
    __syncthreads();
    int t = ntype[i];
    const float* wa = Wa + (size_t)t * DIM * DIM;
    float acc = 0.f;
#pragma unroll 4
    for (int d = 0; d < DIM; ++d)
        acc = fmaf(hs[d], wa[d * DIM + j], acc);
    float gte = 1.f / (1.f + __expf(-skip[t]));
    float xv = x[(size_t)i * DIM + j];
    float y = xv * (2.f - gte) + acc * gte;     // x + (h*g + x*(1-g))
    // block LayerNorm reduce (2 waves)
    float s = y, s2 = y * y;
    for (int o = 32; o > 0; o >>= 1) {
        s  += __shfl_down(s, o, 64);
        s2 += __shfl_down(s2, o, 64);
    }
    int wid = j >> 6;
    if ((j & 63) == 0) { red[wid * 2] = s; red[wid * 2 + 1] = s2; }
    __syncthreads();
    float tot  = red[0] + red[2];
    float tot2 = red[1] + red[3];
    float mu  = tot * (1.f / DIM);
    float var = tot2 * (1.f / DIM) - mu * mu;
    float inv = rsqrtf(var + 1e-5f);
    out[(size_t)i * DIM + j] = (y - mu) * inv * gamma[j] + beta[j];
}

// ======================= launcher =======================

extern "C" void kernel_launch(void* const* d_in, const int* in_sizes, int n_in,
                              void* d_out, int out_size, void* d_ws, size_t ws_size,
                              hipStream_t stream) {
    const float* x       = (const float*)d_in[0];
    const int*   src     = (const int*)d_in[1];
    const int*   dst     = (const int*)d_in[2];
    const int*   ntype   = (const int*)d_in[3];
    const int*   etype   = (const int*)d_in[4];
    const float* Wk      = (const float*)d_in[5];
    const float* Wq      = (const float*)d_in[6];
    const float* Wv      = (const float*)d_in[7];
    const float* Wa      = (const float*)d_in[8];
    const float* rel_pri = (const float*)d_in[9];
    const float* rel_att = (const float*)d_in[10];
    const float* rel_msg = (const float*)d_in[11];
    const float* skip    = (const float*)d_in[12];
    const float* gamma   = (const float*)d_in[13];
    const float* beta    = (const float*)d_in[14];
    float* out = (float*)d_out;

    const int N = N_NODES, E = N_EDGES;

    // workspace layout
    char* ws = (char*)d_ws;
    float* kb   = (float*)ws;                         // N*128
    float* qb   = kb + (size_t)N * DIM;               // N*128
    float* vb   = qb + (size_t)N * DIM;               // N*128
    float* a_ws = vb + (size_t)N * DIM;               // E*8
    int* deg    = (int*)(a_ws + (size_t)E * H_HEADS); // N
    int* offs   = deg + N;                            // N
    int* elist  = offs + N;                           // E
    int* partial = elist + E;                         // 256

    const int nbScan = (N + 255) / 256;               // 196

    // CSR build
    hipMemsetAsync(deg, 0, (size_t)N * sizeof(int), stream);
    k_count<<<(E + 255) / 256, 256, 0, stream>>>(dst, deg, E);
    k_scanA<<<nbScan, 256, 0, stream>>>(deg, offs, partial, N);
    k_scanB<<<1, 256, 0, stream>>>(partial, nbScan);
    k_scanC<<<nbScan, 256, 0, stream>>>(offs, partial, N);
    k_scatter<<<(E + 255) / 256, 256, 0, stream>>>(dst, offs, elist, E);

    // projections
    k_kqv<<<N, DIM, 0, stream>>>(x, ntype, Wk, Wq, Wv, kb, qb, vb);

    // edge logits
    k_edge_a<<<(E * H_HEADS + 255) / 256, 256, 0, stream>>>(
        kb, qb, src, dst, etype, rel_att, rel_pri, a_ws, E);

    // per-node softmax + message aggregation -> d_out (scratch)
    k_aggregate<<<(N + 3) / 4, 256, 0, stream>>>(
        vb, a_ws, offs, deg, elist, src, etype, rel_msg, out, N);

    // output projection + gate + residual + LayerNorm (in place on d_out)
    k_final<<<N, DIM, 0, stream>>>(x, ntype, Wa, skip, gamma, beta, out);
}